// Round 10
// baseline (348.163 us; speedup 1.0000x reference)
//
#include <hip/hip_runtime.h>

#define B_ 256
#define T_ 512
#define K_ 128
#define NT 256
#define DELTA 0.03125f   // fp32-rounding safety margin on the pruning threshold

// DPP fmax step. CTRL: 0x121..0x128 = row_ror 1/2/4/8, 0x142 = row_bcast15,
// 0x143 = row_bcast31. bound_ctrl=false + old=src keeps sourceless lanes
// unchanged (fmax(v,v)=v).
template<int CTRL>
__device__ __forceinline__ float dpp_fmax(float v) {
  int iv = __float_as_int(v);
  int t = __builtin_amdgcn_update_dpp(iv, iv, CTRL, 0xF, 0xF, false);
  return fmaxf(v, __int_as_float(t));
}
__device__ __forceinline__ float rlanef(float v, int lane) {
  return __int_as_float(__builtin_amdgcn_readlane(__float_as_int(v), lane));
}
// state value at global row c (0..127), branchless
__device__ __forceinline__ float rstate(float s0, float s1, int c) {
  const float a = rlanef(s0, c & 63);
  const float b = rlanef(s1, c & 63);
  return (c < 64) ? a : b;
}
// branchless pop of lowest set bit of the 128-bit mask {m0,m1}; pads when empty
__device__ __forceinline__ int popnext(unsigned long long& m0,
                                       unsigned long long& m1, int pad) {
  const int f0 = __ffsll(m0) - 1;     // -1 if empty
  const int f1 = __ffsll(m1) - 1;
  const int c = (f0 >= 0) ? f0 : ((f1 >= 0) ? (f1 + 64) : pad);
  const unsigned long long n0 = m0 & (m0 - 1);
  const unsigned long long n1 = m1 & (m1 - 1);
  m1 = (f0 >= 0) ? m1 : n1;
  m0 = (f0 >= 0) ? n0 : m0;
  return c;
}

// Async global load the compiler can't see (no vmcnt bookkeeping by hipcc).
#define GLOAD(dst, p) \
  asm volatile("global_load_dword %0, %1, off" : "=v"(dst) : "v"(p))

// LDS layout (dynamic, 132608 B):
//   [0, 65536)        float2 Tp[128][64]  -- Tp[i][l] = (T[i][l], T[i][l+64])
//   [65536, 130944)   u8 bp[511][128]
//   [130944, 131966)  u16 code[511]       (i* if |C|==1 else 0xFFFF)
//   [131968, 132480)  u8 tags[512]
//   [132480, ...)     int scratch
__global__ __launch_bounds__(NT) void viterbi_fused(
    const float* __restrict__ pot,     // B,T,K
    const float* __restrict__ trans,   // K,K
    const int*   __restrict__ lens,    // B
    float* __restrict__ out)           // B,T,K one-hot
{
  extern __shared__ __align__(16) char smem[];
  float2*         Tp   = (float2*)smem;
  unsigned char*  bp   = (unsigned char*)(smem + 65536);
  unsigned short* code = (unsigned short*)(smem + 130944);
  unsigned char*  tags = (unsigned char*)(smem + 131968);
  int*            scr  = (int*)(smem + 132480);

  const int tid = threadIdx.x;
  const int b   = blockIdx.x;
  const int L   = lens[b];
  const float* potb = pot + (size_t)b * T_ * K_;
  float4* o4 = (float4*)(out + (size_t)b * T_ * K_);

  // ---- Stage paired transitions to LDS, tracking min/max ----
  float mn = INFINITY, mx = -INFINITY;
  for (int e = tid; e < K_ * 64; e += NT) {
    const int i = e >> 6, ll = e & 63;
    const float a = trans[i * K_ + ll];
    const float c = trans[i * K_ + ll + 64];
    Tp[e] = make_float2(a, c);
    mn = fminf(mn, fminf(a, c));
    mx = fmaxf(mx, fmaxf(a, c));
  }
  float* red = (float*)bp;   // bp area unused until forward loop: scratch
  red[tid] = mn; red[NT + tid] = mx;
  __syncthreads();

  if (tid < 64) {
    // ================= Forward pass: wave 0 =================
    const int l = tid;

    float s0, s1;
    {
      const float* p0 = potb + l;
      const float* p1 = potb + 64 + l;
      GLOAD(s0, p0); GLOAD(s1, p1);
      asm volatile("s_waitcnt vmcnt(0)" : "+v"(s0), "+v"(s1));
    }

    // 4-deep emission ring: 8 outstanding async loads, manual vmcnt
    float e0_0, e1_0, e0_1, e1_1, e0_2, e1_2, e0_3, e1_3;
#define PLOAD(KK)                                                       \
    { int idx = 1 + KK; idx = (idx < L) ? idx : (L - 1);                \
      const float* pp = potb + idx * K_ + l;                            \
      GLOAD(e0_##KK, pp); GLOAD(e1_##KK, pp + 64); }
    PLOAD(0) PLOAD(1) PLOAD(2) PLOAD(3)

    // threshold range (runs while the ring loads fly)
    float rmn = INFINITY, rmx = -INFINITY;
#pragma unroll
    for (int i = 0; i < 4; ++i) {
      rmn = fminf(rmn, red[i * 64 + l]);
      rmx = fmaxf(rmx, red[256 + i * 64 + l]);
    }
    for (int d = 1; d < 64; d <<= 1) {
      rmn = fminf(rmn, __shfl_xor(rmn, d));
      rmx = fmaxf(rmx, __shfl_xor(rmx, d));
    }
    const float Rng = (rmx - rmn) + DELTA;

// One step, straight-line: always process 4 candidates (duplicates of the
// first pad short lists; strict > keeps them exact no-ops). Single rare
// branch for nc>4; single uniform branch for the lane-0 code write.
#define VSTEP(KK, MAIN)                                                        \
    {                                                                          \
      if (MAIN)                                                                \
        asm volatile("s_waitcnt vmcnt(6)" : "+v"(e0_##KK), "+v"(e1_##KK));     \
      float lm = fmaxf(s0, s1);                                                \
      lm = dpp_fmax<0x121>(lm);                                                \
      lm = dpp_fmax<0x122>(lm);                                                \
      lm = dpp_fmax<0x124>(lm);                                                \
      lm = dpp_fmax<0x128>(lm);                                                \
      lm = dpp_fmax<0x142>(lm);                                                \
      lm = dpp_fmax<0x143>(lm);                                                \
      const float thr = rlanef(lm, 63) - Rng;                                  \
      unsigned long long c0m = __ballot(s0 >= thr);                            \
      unsigned long long c1m = __ballot(s1 >= thr);                            \
      const int nc = __popcll(c0m) + __popcll(c1m);                            \
      c0m = (c0m | c1m) ? c0m : 1ull;       /* unreachable guard */            \
      const int ca = popnext(c0m, c1m, 0);                                     \
      const int cb = popnext(c0m, c1m, ca);                                    \
      const int cc = popnext(c0m, c1m, ca);                                    \
      const int cd = popnext(c0m, c1m, ca);                                    \
      const float sa = rstate(s0, s1, ca);                                     \
      const float sb = rstate(s0, s1, cb);                                     \
      const float sc = rstate(s0, s1, cc);                                     \
      const float sd = rstate(s0, s1, cd);                                     \
      const float2 ta = Tp[(ca << 6) + l];                                     \
      const float2 tb = Tp[(cb << 6) + l];                                     \
      const float2 tc = Tp[(cc << 6) + l];                                     \
      const float2 td = Tp[(cd << 6) + l];                                     \
      float m0 = sa + ta.x, m1 = sa + ta.y;                                    \
      int i0 = ca, i1 = ca;                                                    \
      { const float v0 = sb + tb.x, v1 = sb + tb.y;                            \
        if (v0 > m0) { m0 = v0; i0 = cb; }                                     \
        if (v1 > m1) { m1 = v1; i1 = cb; } }                                   \
      { const float v0 = sc + tc.x, v1 = sc + tc.y;                            \
        if (v0 > m0) { m0 = v0; i0 = cc; }                                     \
        if (v1 > m1) { m1 = v1; i1 = cc; } }                                   \
      { const float v0 = sd + td.x, v1 = sd + td.y;                            \
        if (v0 > m0) { m0 = v0; i0 = cd; }                                     \
        if (v1 > m1) { m1 = v1; i1 = cd; } }                                   \
      if (nc > 4) {                         /* rare exact fallback */          \
        int rem = nc - 4, pv = cd;                                             \
        while (rem-- > 0) {                                                    \
          const int c = popnext(c0m, c1m, pv); pv = c;                         \
          const float sv = rstate(s0, s1, c);                                  \
          const float2 tv = Tp[(c << 6) + l];                                  \
          const float v0 = sv + tv.x, v1 = sv + tv.y;                          \
          if (v0 > m0) { m0 = v0; i0 = c; }                                    \
          if (v1 > m1) { m1 = v1; i1 = c; }                                    \
        }                                                                      \
      }                                                                        \
      s0 = e0_##KK + m0; s1 = e1_##KK + m1;                                    \
      bp[(t + KK - 1) * K_ + l]      = (unsigned char)i0;                      \
      bp[(t + KK - 1) * K_ + 64 + l] = (unsigned char)i1;                      \
      if (l == 0) code[t + KK - 1] = (nc == 1) ? (unsigned short)ca            \
                                               : (unsigned short)0xFFFF;       \
      if (MAIN) {                                                              \
        int idx = t + KK + 4; idx = (idx < L) ? idx : (L - 1);                 \
        const float* pp = potb + idx * K_ + l;                                 \
        GLOAD(e0_##KK, pp); GLOAD(e1_##KK, pp + 64);                           \
      }                                                                        \
    }

    int t = 1;
    while (t + 4 <= L) {
      VSTEP(0, true) VSTEP(1, true) VSTEP(2, true) VSTEP(3, true)
      t += 4;
    }
    // drain: all ring registers valid after this
    asm volatile("s_waitcnt vmcnt(0)"
      : "+v"(e0_0), "+v"(e1_0), "+v"(e0_1), "+v"(e1_1),
        "+v"(e0_2), "+v"(e1_2), "+v"(e0_3), "+v"(e1_3));
    // guarded static tail (<= 3 steps, emissions already in regs)
    if (t + 0 < L) VSTEP(0, false)
    if (t + 1 < L) VSTEP(1, false)
    if (t + 2 < L) VSTEP(2, false)

    // final argmax (first occurrence)
    float bv = s0; int bi = l;
    if (s1 > bv) { bv = s1; bi = l + 64; }
    for (int d = 1; d < 64; d <<= 1) {
      const float ov = __shfl_xor(bv, d);
      const int   oi = __shfl_xor(bi, d);
      if (ov > bv || (ov == bv && oi < bi)) { bv = ov; bi = oi; }
    }
    if (l == 0) { tags[L - 1] = (unsigned char)bi; scr[0] = bi; }
  } else {
    // ======== Waves 1-3: write one-hot rows [L, T) concurrently ========
    const int wtid = tid - 64;                 // 0..191
    const int n4 = (T_ - L) * 32;
    for (int e = wtid; e < n4; e += 192) {
      const int row = L + (e >> 5);
      const int q   = e & 31;
      float4 v = make_float4(q == 0 ? 1.0f : 0.0f, 0.0f, 0.0f, 0.0f);
      o4[row * 32 + q] = v;
    }
  }
  __syncthreads();

  // ---- Backtrace: parallel segments anchored at |C|==1 steps ----
  const int bestTag = scr[0];
  for (int p = tid; p < L - 1; p += NT) {
    const unsigned short c = code[p];
    if (c != 0xFFFF) {                 // anchor: tag known regardless of future
      int tg = c;
      tags[p] = (unsigned char)tg;
      int q = p - 1;
      while (q >= 0 && code[q] == 0xFFFF) {
        tg = bp[q * K_ + tg];
        tags[q] = (unsigned char)tg;
        --q;
      }
    }
  }
  if (tid == 0 && L >= 2) {            // top segment from the final argmax
    int tg = bestTag;
    int q = L - 2;
    while (q >= 0 && code[q] == 0xFFFF) {
      tg = bp[q * K_ + tg];
      tags[q] = (unsigned char)tg;
      --q;
    }
  }
  __syncthreads();

  // ---- One-hot write for rows [0, L) (rows >= L already written) ----
  for (int i = tid; i < (L << 5); i += NT) {
    const int p  = i >> 5;
    const int tg = tags[p];
    const int k  = (i & 31) * 4;
    float4 v;
    v.x = (k     == tg) ? 1.0f : 0.0f;
    v.y = (k + 1 == tg) ? 1.0f : 0.0f;
    v.z = (k + 2 == tg) ? 1.0f : 0.0f;
    v.w = (k + 3 == tg) ? 1.0f : 0.0f;
    o4[i] = v;
  }
}

extern "C" void kernel_launch(void* const* d_in, const int* in_sizes, int n_in,
                              void* d_out, int out_size, void* d_ws, size_t ws_size,
                              hipStream_t stream) {
  const float* pot   = (const float*)d_in[0];
  const float* trans = (const float*)d_in[1];
  const int*   lens  = (const int*)d_in[2];
  float* out = (float*)d_out;

  viterbi_fused<<<B_, NT, 132608, stream>>>(pot, trans, lens, out);
}